// Round 5
// baseline (1186.965 us; speedup 1.0000x reference)
//
#include <hip/hip_runtime.h>

// Diffeomorphic transform (scaling & squaring), 7 steps.
// flow: [1, 3, 192, 192, 192] fp32, c=0 -> z disp, c=1 -> y, c=2 -> x.
// out = f + trilinear_sample(f, voxel + f*(size-1)/2), border clamp,
// align_corners=True (identity unnormalizes to voxel index).
//
// R2: XCD z-chunk swizzle (kept). R3: channel-interleaved intermediates
// (kept; compiler emits dwordx3 gathers). R5: y-strip blocked schedule so the
// per-XCD gather window ((24+2*sigma)y x (2*sigma+1)z x 192x x 12B ~ 3-4 MB)
// fits the 4 MiB XCD L2 -- R4 counters showed HBM 3.4%, VALU 15%: the 180us
// was L2-thrash -> L3-BW on ~1.8 GB of gather line fills. Plus nontemporal
// dst stores (written buffer is dead this dispatch; don't churn L2).

constexpr int DD = 192, HH = 192, WW = 192;
constexpr int NN = DD * HH * WW;
constexpr int NXCD = 8;
constexpr int ZCH = DD / NXCD;        // 24 z-planes per XCD
constexpr int YSTRIP = 24;            // y rows per strip
constexpr int NB = NXCD * ZCH * HH;   // 36864 blocks of 192 threads (one x-row)

struct F3 { float x, y, z; };         // 12B, align 4 -> dwordx3

// SES/SCS: src element/channel stride; DES/DCS: dst. Planar (1,NN), interleaved (3,1).
template <int SES, int SCS, int DES, int DCS>
__global__ __launch_bounds__(192) void diffeo_step(
    const float* __restrict__ src, float* __restrict__ dst, float scale)
{
    // Block decode (all scalar): consecutive hw blocks round-robin XCDs.
    // Per-XCD order: strip-major, then z, then y -> small resident window.
    int bid = blockIdx.x;
    int xcd = bid & (NXCD - 1);
    int lin = bid >> 3;                 // 0..4607 per-XCD sequence
    int y_l = lin % YSTRIP;
    int zt  = lin / YSTRIP;             // 0..191
    int z_l = zt % ZCH;
    int s   = zt / ZCH;                 // strip 0..7
    int h = s * YSTRIP + y_l;           // y
    int d = xcd * ZCH + z_l;            // z
    int w = threadIdx.x;                // x
    int idx = (d * HH + h) * WW + w;

    float f0, f1, f2;
    if constexpr (SES == 3) {
        F3 own = *reinterpret_cast<const F3*>(src + idx * 3);
        f0 = own.x * scale; f1 = own.y * scale; f2 = own.z * scale;
    } else {
        f0 = src[idx]          * scale;
        f1 = src[idx + NN]     * scale;
        f2 = src[idx + 2 * NN] * scale;
    }

    float x = fminf(fmaxf((float)w + f2 * (0.5f * (WW - 1)), 0.0f), (float)(WW - 1));
    float y = fminf(fmaxf((float)h + f1 * (0.5f * (HH - 1)), 0.0f), (float)(HH - 1));
    float z = fminf(fmaxf((float)d + f0 * (0.5f * (DD - 1)), 0.0f), (float)(DD - 1));

    int x0 = (int)x;  float wx = x - (float)x0;
    int y0 = (int)y;  float wy = y - (float)y0;
    int z0 = (int)z;  float wz = z - (float)z0;
    int x1 = min(x0 + 1, WW - 1);
    int y1 = min(y0 + 1, HH - 1);
    int z1 = min(z0 + 1, DD - 1);

    float ox = 1.0f - wx, oy = 1.0f - wy, oz = 1.0f - wz;
    float w000 = ox * oy * oz, w001 = wx * oy * oz;
    float w010 = ox * wy * oz, w011 = wx * wy * oz;
    float w100 = ox * oy * wz, w101 = wx * oy * wz;
    float w110 = ox * wy * wz, w111 = wx * wy * wz;

    int i000 = (z0 * HH + y0) * WW + x0;
    int i001 = (z0 * HH + y0) * WW + x1;
    int i010 = (z0 * HH + y1) * WW + x0;
    int i011 = (z0 * HH + y1) * WW + x1;
    int i100 = (z1 * HH + y0) * WW + x0;
    int i101 = (z1 * HH + y0) * WW + x1;
    int i110 = (z1 * HH + y1) * WW + x0;
    int i111 = (z1 * HH + y1) * WW + x1;

    float v0, v1, v2;
    if constexpr (SES == 3) {
        const F3* s3 = reinterpret_cast<const F3*>(src);
        F3 c000 = s3[i000], c001 = s3[i001], c010 = s3[i010], c011 = s3[i011];
        F3 c100 = s3[i100], c101 = s3[i101], c110 = s3[i110], c111 = s3[i111];
        v0 = w000 * c000.x + w001 * c001.x + w010 * c010.x + w011 * c011.x
           + w100 * c100.x + w101 * c101.x + w110 * c110.x + w111 * c111.x;
        v1 = w000 * c000.y + w001 * c001.y + w010 * c010.y + w011 * c011.y
           + w100 * c100.y + w101 * c101.y + w110 * c110.y + w111 * c111.y;
        v2 = w000 * c000.z + w001 * c001.z + w010 * c010.z + w011 * c011.z
           + w100 * c100.z + w101 * c101.z + w110 * c110.z + w111 * c111.z;
    } else {
        float acc[3];
#pragma unroll
        for (int c = 0; c < 3; ++c) {
            const float* s = src + c * SCS;
            acc[c] =
                w000 * s[i000] + w001 * s[i001] +
                w010 * s[i010] + w011 * s[i011] +
                w100 * s[i100] + w101 * s[i101] +
                w110 * s[i110] + w111 * s[i111];
        }
        v0 = acc[0]; v1 = acc[1]; v2 = acc[2];
    }

    float o0 = f0 + scale * v0;
    float o1 = f1 + scale * v1;
    float o2 = f2 + scale * v2;
    if constexpr (DES == 3) {
        __builtin_nontemporal_store(o0, dst + idx * 3 + 0);
        __builtin_nontemporal_store(o1, dst + idx * 3 + 1);
        __builtin_nontemporal_store(o2, dst + idx * 3 + 2);
    } else {
        __builtin_nontemporal_store(o0, dst + idx);
        __builtin_nontemporal_store(o1, dst + idx + NN);
        __builtin_nontemporal_store(o2, dst + idx + 2 * NN);
    }
}

extern "C" void kernel_launch(void* const* d_in, const int* in_sizes, int n_in,
                              void* d_out, int out_size, void* d_ws, size_t ws_size,
                              hipStream_t stream) {
    const float* in = (const float*)d_in[0];
    float* out = (float*)d_out;
    float* ws  = (float*)d_ws;

    const float inv = 1.0f / 128.0f;  // 2^-TIME_STEP, TIME_STEP=7

    // Layouts: input planar; intermediates interleaved; final output planar.
    diffeo_step<1, NN, 3, 1><<<NB, 192, 0, stream>>>(in,  out, inv);   // it1
    diffeo_step<3, 1,  3, 1><<<NB, 192, 0, stream>>>(out, ws,  1.0f);  // it2
    diffeo_step<3, 1,  3, 1><<<NB, 192, 0, stream>>>(ws,  out, 1.0f);  // it3
    diffeo_step<3, 1,  3, 1><<<NB, 192, 0, stream>>>(out, ws,  1.0f);  // it4
    diffeo_step<3, 1,  3, 1><<<NB, 192, 0, stream>>>(ws,  out, 1.0f);  // it5
    diffeo_step<3, 1,  3, 1><<<NB, 192, 0, stream>>>(out, ws,  1.0f);  // it6
    diffeo_step<3, 1,  1, NN><<<NB, 192, 0, stream>>>(ws,  out, 1.0f); // it7
}

// Round 8
// 1182.002 us; speedup vs baseline: 1.0042x; 1.0042x over previous
//
#include <hip/hip_runtime.h>

// Diffeomorphic transform (scaling & squaring), 7 steps.
// flow: [1, 3, 192, 192, 192] fp32, c=0 -> z disp, c=1 -> y, c=2 -> x.
// out = f + trilinear_sample(f, voxel + f*(size-1)/2), border clamp,
// align_corners=True (identity unnormalizes to voxel index).
//
// R8: EXACT fp32 storage only (R6 fp16 / R7 int21 both failed: the iteration
// is chaotic -- stored-value error eps -> 95.5*eps position error, amplified
// ~1e4-1e5x over remaining steps; even 2^-16 quantization exceeds the 0.0528
// budget). Attack line-fills instead: 16B float4 records in a 2x2x2-voxel
// TILED layout (tile = 8 records = 512B). A trilinear 2x2x2 neighborhood
// touches E[(1.5)^3] = 3.375 cache lines vs 5.25 for row-major 12B F3
// (each axis pair (c,c+1) is in-tile with prob 1/2). Two 113MB buffers fit
// the confirmed >=227MB ws. R2 XCD z-chunk swizzle kept. F3 fallback kept.

constexpr int DD = 192, HH = 192, WW = 192;
constexpr int NN = DD * HH * WW;
constexpr int NB = NN / 256;      // 27648 blocks
constexpr int NXCD = 8;
constexpr int CHUNK = NB / NXCD;  // 3456 (exact -> bijective swizzle)
constexpr int TT = WW / 2;        // 96 tiles per axis

struct F3 { float x, y, z; };     // 12B fallback record

// Record index (units of float4) in the 2x2x2-tiled layout. Bijection on [0,NN).
__device__ __forceinline__ int rec_addr(int z, int y, int x) {
    return ((((z >> 1) * TT + (y >> 1)) * TT + (x >> 1)) << 3)
         + (((z & 1) << 2) | ((y & 1) << 1) | (x & 1));
}

// Modes: 0 = planar fp32 (stride NN/channel), 1 = tiled float4, 2 = F3 12B.
template <int SM, int DM>
__global__ __launch_bounds__(256) void diffeo_step(
    const void* __restrict__ srcv, void* __restrict__ dstv, float scale)
{
    int bid = blockIdx.x;
    int swz = (bid & (NXCD - 1)) * CHUNK + (bid >> 3);
    int idx = swz * 256 + threadIdx.x;

    int w = idx % WW;
    int t = idx / WW;
    int h = t % HH;
    int d = t / HH;

    float f0, f1, f2;
    if constexpr (SM == 0) {
        const float* src = (const float*)srcv;
        f0 = src[idx] * scale;
        f1 = src[idx + NN] * scale;
        f2 = src[idx + 2 * NN] * scale;
    } else if constexpr (SM == 1) {
        const float4* s4 = (const float4*)srcv;
        float4 own = s4[rec_addr(d, h, w)];
        f0 = own.x * scale; f1 = own.y * scale; f2 = own.z * scale;
    } else {
        const F3* s3 = (const F3*)srcv;
        F3 own = s3[idx];
        f0 = own.x * scale; f1 = own.y * scale; f2 = own.z * scale;
    }

    float x = fminf(fmaxf((float)w + f2 * (0.5f * (WW - 1)), 0.0f), (float)(WW - 1));
    float y = fminf(fmaxf((float)h + f1 * (0.5f * (HH - 1)), 0.0f), (float)(HH - 1));
    float z = fminf(fmaxf((float)d + f0 * (0.5f * (DD - 1)), 0.0f), (float)(DD - 1));

    int x0 = (int)x;  float wx = x - (float)x0;
    int y0 = (int)y;  float wy = y - (float)y0;
    int z0 = (int)z;  float wz = z - (float)z0;
    int x1 = min(x0 + 1, WW - 1);
    int y1 = min(y0 + 1, HH - 1);
    int z1 = min(z0 + 1, DD - 1);

    float ox = 1.0f - wx, oy = 1.0f - wy, oz = 1.0f - wz;
    float w000 = ox * oy * oz, w001 = wx * oy * oz;
    float w010 = ox * wy * oz, w011 = wx * wy * oz;
    float w100 = ox * oy * wz, w101 = wx * oy * wz;
    float w110 = ox * wy * wz, w111 = wx * wy * wz;

    float v0, v1, v2;
    if constexpr (SM == 0) {
        const float* src = (const float*)srcv;
        int i000 = (z0 * HH + y0) * WW + x0, i001 = (z0 * HH + y0) * WW + x1;
        int i010 = (z0 * HH + y1) * WW + x0, i011 = (z0 * HH + y1) * WW + x1;
        int i100 = (z1 * HH + y0) * WW + x0, i101 = (z1 * HH + y0) * WW + x1;
        int i110 = (z1 * HH + y1) * WW + x0, i111 = (z1 * HH + y1) * WW + x1;
        float acc[3];
#pragma unroll
        for (int c = 0; c < 3; ++c) {
            const float* s = src + c * NN;
            acc[c] =
                w000 * s[i000] + w001 * s[i001] +
                w010 * s[i010] + w011 * s[i011] +
                w100 * s[i100] + w101 * s[i101] +
                w110 * s[i110] + w111 * s[i111];
        }
        v0 = acc[0]; v1 = acc[1]; v2 = acc[2];
    } else if constexpr (SM == 1) {
        const float4* s4 = (const float4*)srcv;
        float4 c000 = s4[rec_addr(z0, y0, x0)];
        float4 c001 = s4[rec_addr(z0, y0, x1)];
        float4 c010 = s4[rec_addr(z0, y1, x0)];
        float4 c011 = s4[rec_addr(z0, y1, x1)];
        float4 c100 = s4[rec_addr(z1, y0, x0)];
        float4 c101 = s4[rec_addr(z1, y0, x1)];
        float4 c110 = s4[rec_addr(z1, y1, x0)];
        float4 c111 = s4[rec_addr(z1, y1, x1)];
        v0 = w000 * c000.x + w001 * c001.x + w010 * c010.x + w011 * c011.x
           + w100 * c100.x + w101 * c101.x + w110 * c110.x + w111 * c111.x;
        v1 = w000 * c000.y + w001 * c001.y + w010 * c010.y + w011 * c011.y
           + w100 * c100.y + w101 * c101.y + w110 * c110.y + w111 * c111.y;
        v2 = w000 * c000.z + w001 * c001.z + w010 * c010.z + w011 * c011.z
           + w100 * c100.z + w101 * c101.z + w110 * c110.z + w111 * c111.z;
    } else {
        const F3* s3 = (const F3*)srcv;
        int i000 = (z0 * HH + y0) * WW + x0, i001 = (z0 * HH + y0) * WW + x1;
        int i010 = (z0 * HH + y1) * WW + x0, i011 = (z0 * HH + y1) * WW + x1;
        int i100 = (z1 * HH + y0) * WW + x0, i101 = (z1 * HH + y0) * WW + x1;
        int i110 = (z1 * HH + y1) * WW + x0, i111 = (z1 * HH + y1) * WW + x1;
        F3 c000 = s3[i000], c001 = s3[i001], c010 = s3[i010], c011 = s3[i011];
        F3 c100 = s3[i100], c101 = s3[i101], c110 = s3[i110], c111 = s3[i111];
        v0 = w000 * c000.x + w001 * c001.x + w010 * c010.x + w011 * c011.x
           + w100 * c100.x + w101 * c101.x + w110 * c110.x + w111 * c111.x;
        v1 = w000 * c000.y + w001 * c001.y + w010 * c010.y + w011 * c011.y
           + w100 * c100.y + w101 * c101.y + w110 * c110.y + w111 * c111.y;
        v2 = w000 * c000.z + w001 * c001.z + w010 * c010.z + w011 * c011.z
           + w100 * c100.z + w101 * c101.z + w110 * c110.z + w111 * c111.z;
    }

    float o0 = f0 + scale * v0;
    float o1 = f1 + scale * v1;
    float o2 = f2 + scale * v2;
    if constexpr (DM == 0) {
        float* dst = (float*)dstv;
        dst[idx] = o0; dst[idx + NN] = o1; dst[idx + 2 * NN] = o2;
    } else if constexpr (DM == 1) {
        float4* d4 = (float4*)dstv;
        d4[rec_addr(d, h, w)] = make_float4(o0, o1, o2, 0.0f);
    } else {
        F3* d3 = (F3*)dstv;
        F3 o = { o0, o1, o2 };
        d3[idx] = o;
    }
}

extern "C" void kernel_launch(void* const* d_in, const int* in_sizes, int n_in,
                              void* d_out, int out_size, void* d_ws, size_t ws_size,
                              hipStream_t stream) {
    const void* in = d_in[0];
    void* out = d_out;
    const float inv = 1.0f / 128.0f;  // 2^-TIME_STEP, TIME_STEP=7

    // Tiled path needs two float4*NN buffers (32B/voxel total) in ws.
    if (ws_size >= (size_t)NN * 32) {
        float4* qa = (float4*)d_ws;        // buffer A (113 MB)
        float4* qb = (float4*)d_ws + NN;   // buffer B (113 MB)
        diffeo_step<0, 1><<<NB, 256, 0, stream>>>(in, qa, inv);    // it1
        diffeo_step<1, 1><<<NB, 256, 0, stream>>>(qa, qb, 1.0f);   // it2
        diffeo_step<1, 1><<<NB, 256, 0, stream>>>(qb, qa, 1.0f);   // it3
        diffeo_step<1, 1><<<NB, 256, 0, stream>>>(qa, qb, 1.0f);   // it4
        diffeo_step<1, 1><<<NB, 256, 0, stream>>>(qb, qa, 1.0f);   // it5
        diffeo_step<1, 1><<<NB, 256, 0, stream>>>(qa, qb, 1.0f);   // it6
        diffeo_step<1, 0><<<NB, 256, 0, stream>>>(qb, out, 1.0f);  // it7
    } else {
        // Fallback: F3 12B interleaved ping-pong (R3/R4 proven path).
        void* ws = d_ws;
        diffeo_step<0, 2><<<NB, 256, 0, stream>>>(in,  out, inv);
        diffeo_step<2, 2><<<NB, 256, 0, stream>>>(out, ws,  1.0f);
        diffeo_step<2, 2><<<NB, 256, 0, stream>>>(ws,  out, 1.0f);
        diffeo_step<2, 2><<<NB, 256, 0, stream>>>(out, ws,  1.0f);
        diffeo_step<2, 2><<<NB, 256, 0, stream>>>(ws,  out, 1.0f);
        diffeo_step<2, 2><<<NB, 256, 0, stream>>>(out, ws,  1.0f);
        diffeo_step<2, 0><<<NB, 256, 0, stream>>>(ws,  out, 1.0f);
    }
}

// Round 9
// 754.653 us; speedup vs baseline: 1.5729x; 1.5663x over previous
//
#include <hip/hip_runtime.h>

// Diffeomorphic transform (scaling & squaring), 7 steps.
// flow: [1, 3, 192, 192, 192] fp32, c=0 -> z disp, c=1 -> y, c=2 -> x.
// out = f + trilinear_sample(f, voxel + f*(size-1)/2), border clamp,
// align_corners=True (identity unnormalizes to voxel index).
//
// R9: exact fp32 only (R6 fp16 / R7 int21 failed: chaotic amplification of
// storage error). Storage: float4 records in 2x2x2-voxel tiles (tile = 8
// records = 512B, aligned); a trilinear 2x2x2 footprint touches E=3.375
// distinct 64B lines vs 5.25 row-major, and no record straddles a line.
// NEW vs R8: thread mapping is ALSO tiled (thread record index == gid), so
// own-reads/writes are fully-coalesced full-line streams -- R8 wrote 32B
// half-lines from row-major waves and paid 2x HBM write (167MB, +39us).
// R2 XCD z-chunk swizzle kept. F3 12B fallback kept for small ws.

constexpr int DD = 192, HH = 192, WW = 192;
constexpr int NN = DD * HH * WW;
constexpr int NB = NN / 256;      // 27648 blocks
constexpr int NXCD = 8;
constexpr int CHUNK = NB / NXCD;  // 3456 (exact -> bijective swizzle)
constexpr int TT = WW / 2;        // 96 tiles per axis

struct F3 { float x, y, z; };     // 12B fallback record

// Record index (units of float4) in the 2x2x2-tiled layout. Bijection on [0,NN).
__device__ __forceinline__ int rec_addr(int z, int y, int x) {
    return ((((z >> 1) * TT + (y >> 1)) * TT + (x >> 1)) << 3)
         + (((z & 1) << 2) | ((y & 1) << 1) | (x & 1));
}

// Modes: 0 = planar fp32 (stride NN/channel), 1 = tiled float4 (tiled thread
// order), 2 = F3 12B row-major (fallback, row-major thread order).
template <int SM, int DM>
__global__ __launch_bounds__(256) void diffeo_step(
    const void* __restrict__ srcv, void* __restrict__ dstv, float scale)
{
    int bid = blockIdx.x;
    int swz = (bid & (NXCD - 1)) * CHUNK + (bid >> 3);
    int gid = swz * 256 + threadIdx.x;

    int w, h, d;
    if constexpr (SM == 1 || DM == 1) {
        // gid is a record index in tiled space; decode voxel coords.
        int slot = gid & 7;
        int tile = gid >> 3;
        int tx = tile % TT;
        int t2 = tile / TT;
        int ty = t2 % TT;
        int tz = t2 / TT;
        w = (tx << 1) | (slot & 1);
        h = (ty << 1) | ((slot >> 1) & 1);
        d = (tz << 1) | (slot >> 2);
    } else {
        // gid is a row-major voxel index.
        w = gid % WW;
        int t = gid / WW;
        h = t % HH;
        d = t / HH;
    }
    int idx = (d * HH + h) * WW + w;   // row-major voxel index (planar I/O)

    float f0, f1, f2;
    if constexpr (SM == 0) {
        const float* src = (const float*)srcv;
        f0 = src[idx] * scale;
        f1 = src[idx + NN] * scale;
        f2 = src[idx + 2 * NN] * scale;
    } else if constexpr (SM == 1) {
        const float4* s4 = (const float4*)srcv;
        float4 own = s4[gid];                    // coalesced: record idx == gid
        f0 = own.x * scale; f1 = own.y * scale; f2 = own.z * scale;
    } else {
        const F3* s3 = (const F3*)srcv;
        F3 own = s3[gid];
        f0 = own.x * scale; f1 = own.y * scale; f2 = own.z * scale;
    }

    float x = fminf(fmaxf((float)w + f2 * (0.5f * (WW - 1)), 0.0f), (float)(WW - 1));
    float y = fminf(fmaxf((float)h + f1 * (0.5f * (HH - 1)), 0.0f), (float)(HH - 1));
    float z = fminf(fmaxf((float)d + f0 * (0.5f * (DD - 1)), 0.0f), (float)(DD - 1));

    int x0 = (int)x;  float wx = x - (float)x0;
    int y0 = (int)y;  float wy = y - (float)y0;
    int z0 = (int)z;  float wz = z - (float)z0;
    int x1 = min(x0 + 1, WW - 1);
    int y1 = min(y0 + 1, HH - 1);
    int z1 = min(z0 + 1, DD - 1);

    float ox = 1.0f - wx, oy = 1.0f - wy, oz = 1.0f - wz;
    float w000 = ox * oy * oz, w001 = wx * oy * oz;
    float w010 = ox * wy * oz, w011 = wx * wy * oz;
    float w100 = ox * oy * wz, w101 = wx * oy * wz;
    float w110 = ox * wy * wz, w111 = wx * wy * wz;

    float v0, v1, v2;
    if constexpr (SM == 0) {
        const float* src = (const float*)srcv;
        int i000 = (z0 * HH + y0) * WW + x0, i001 = (z0 * HH + y0) * WW + x1;
        int i010 = (z0 * HH + y1) * WW + x0, i011 = (z0 * HH + y1) * WW + x1;
        int i100 = (z1 * HH + y0) * WW + x0, i101 = (z1 * HH + y0) * WW + x1;
        int i110 = (z1 * HH + y1) * WW + x0, i111 = (z1 * HH + y1) * WW + x1;
        float acc[3];
#pragma unroll
        for (int c = 0; c < 3; ++c) {
            const float* s = src + c * NN;
            acc[c] =
                w000 * s[i000] + w001 * s[i001] +
                w010 * s[i010] + w011 * s[i011] +
                w100 * s[i100] + w101 * s[i101] +
                w110 * s[i110] + w111 * s[i111];
        }
        v0 = acc[0]; v1 = acc[1]; v2 = acc[2];
    } else if constexpr (SM == 1) {
        const float4* s4 = (const float4*)srcv;
        float4 c000 = s4[rec_addr(z0, y0, x0)];
        float4 c001 = s4[rec_addr(z0, y0, x1)];
        float4 c010 = s4[rec_addr(z0, y1, x0)];
        float4 c011 = s4[rec_addr(z0, y1, x1)];
        float4 c100 = s4[rec_addr(z1, y0, x0)];
        float4 c101 = s4[rec_addr(z1, y0, x1)];
        float4 c110 = s4[rec_addr(z1, y1, x0)];
        float4 c111 = s4[rec_addr(z1, y1, x1)];
        v0 = w000 * c000.x + w001 * c001.x + w010 * c010.x + w011 * c011.x
           + w100 * c100.x + w101 * c101.x + w110 * c110.x + w111 * c111.x;
        v1 = w000 * c000.y + w001 * c001.y + w010 * c010.y + w011 * c011.y
           + w100 * c100.y + w101 * c101.y + w110 * c110.y + w111 * c111.y;
        v2 = w000 * c000.z + w001 * c001.z + w010 * c010.z + w011 * c011.z
           + w100 * c100.z + w101 * c101.z + w110 * c110.z + w111 * c111.z;
    } else {
        const F3* s3 = (const F3*)srcv;
        int i000 = (z0 * HH + y0) * WW + x0, i001 = (z0 * HH + y0) * WW + x1;
        int i010 = (z0 * HH + y1) * WW + x0, i011 = (z0 * HH + y1) * WW + x1;
        int i100 = (z1 * HH + y0) * WW + x0, i101 = (z1 * HH + y0) * WW + x1;
        int i110 = (z1 * HH + y1) * WW + x0, i111 = (z1 * HH + y1) * WW + x1;
        F3 c000 = s3[i000], c001 = s3[i001], c010 = s3[i010], c011 = s3[i011];
        F3 c100 = s3[i100], c101 = s3[i101], c110 = s3[i110], c111 = s3[i111];
        v0 = w000 * c000.x + w001 * c001.x + w010 * c010.x + w011 * c011.x
           + w100 * c100.x + w101 * c101.x + w110 * c110.x + w111 * c111.x;
        v1 = w000 * c000.y + w001 * c001.y + w010 * c010.y + w011 * c011.y
           + w100 * c100.y + w101 * c101.y + w110 * c110.y + w111 * c111.y;
        v2 = w000 * c000.z + w001 * c001.z + w010 * c010.z + w011 * c011.z
           + w100 * c100.z + w101 * c101.z + w110 * c110.z + w111 * c111.z;
    }

    float o0 = f0 + scale * v0;
    float o1 = f1 + scale * v1;
    float o2 = f2 + scale * v2;
    if constexpr (DM == 0) {
        float* dst = (float*)dstv;
        dst[idx] = o0; dst[idx + NN] = o1; dst[idx + 2 * NN] = o2;
    } else if constexpr (DM == 1) {
        float4* d4 = (float4*)dstv;
        d4[gid] = make_float4(o0, o1, o2, 0.0f);   // coalesced full lines
    } else {
        F3* d3 = (F3*)dstv;
        F3 o = { o0, o1, o2 };
        d3[gid] = o;
    }
}

extern "C" void kernel_launch(void* const* d_in, const int* in_sizes, int n_in,
                              void* d_out, int out_size, void* d_ws, size_t ws_size,
                              hipStream_t stream) {
    const void* in = d_in[0];
    void* out = d_out;
    const float inv = 1.0f / 128.0f;  // 2^-TIME_STEP, TIME_STEP=7

    // Tiled path needs two float4*NN buffers (32B/voxel total) in ws.
    if (ws_size >= (size_t)NN * 32) {
        float4* qa = (float4*)d_ws;        // buffer A (113 MB)
        float4* qb = (float4*)d_ws + NN;   // buffer B (113 MB)
        diffeo_step<0, 1><<<NB, 256, 0, stream>>>(in, qa, inv);    // it1
        diffeo_step<1, 1><<<NB, 256, 0, stream>>>(qa, qb, 1.0f);   // it2
        diffeo_step<1, 1><<<NB, 256, 0, stream>>>(qb, qa, 1.0f);   // it3
        diffeo_step<1, 1><<<NB, 256, 0, stream>>>(qa, qb, 1.0f);   // it4
        diffeo_step<1, 1><<<NB, 256, 0, stream>>>(qb, qa, 1.0f);   // it5
        diffeo_step<1, 1><<<NB, 256, 0, stream>>>(qa, qb, 1.0f);   // it6
        diffeo_step<1, 0><<<NB, 256, 0, stream>>>(qb, out, 1.0f);  // it7
    } else {
        // Fallback: F3 12B interleaved ping-pong (R3/R4 proven path).
        void* ws = d_ws;
        diffeo_step<0, 2><<<NB, 256, 0, stream>>>(in,  out, inv);
        diffeo_step<2, 2><<<NB, 256, 0, stream>>>(out, ws,  1.0f);
        diffeo_step<2, 2><<<NB, 256, 0, stream>>>(ws,  out, 1.0f);
        diffeo_step<2, 2><<<NB, 256, 0, stream>>>(out, ws,  1.0f);
        diffeo_step<2, 2><<<NB, 256, 0, stream>>>(ws,  out, 1.0f);
        diffeo_step<2, 2><<<NB, 256, 0, stream>>>(out, ws,  1.0f);
        diffeo_step<2, 0><<<NB, 256, 0, stream>>>(ws,  out, 1.0f);
    }
}

// Round 10
// 650.282 us; speedup vs baseline: 1.8253x; 1.1605x over previous
//
#include <hip/hip_runtime.h>

// Diffeomorphic transform (scaling & squaring), 7 steps.
// flow: [1, 3, 192, 192, 192] fp32, c=0 -> z disp, c=1 -> y, c=2 -> x.
// out = f + trilinear_sample(f, voxel + f*(size-1)/2), border clamp,
// align_corners=True (identity unnormalizes to voxel index).
//
// R9 (kept): exact fp32 float4 records in 2x2x2-voxel tiles, tiled thread
// mapping (coalesced own-read/write), XCD z-chunk swizzle, F3 fallback.
// R10: force all 8 gather loads into flight simultaneously. R9's VGPR=32
// proves the compiler serialized the gathers (~4 in flight); Little's law at
// ~500cy miss latency caps fills at ~17 TB/s == observed. Explicit f4 locals
// + empty asm fence ("+v" on all 8) makes the loads issue back-to-back and
// complete together before the FMA chain (~60 VGPR, still <=64 so occupancy
// stays at 8 waves/SIMD).

constexpr int DD = 192, HH = 192, WW = 192;
constexpr int NN = DD * HH * WW;
constexpr int NB = NN / 256;      // 27648 blocks
constexpr int NXCD = 8;
constexpr int CHUNK = NB / NXCD;  // 3456 (exact -> bijective swizzle)
constexpr int TT = WW / 2;        // 96 tiles per axis

struct F3 { float x, y, z; };     // 12B fallback record
typedef float f4 __attribute__((ext_vector_type(4)));  // 16B, asm-friendly

// Record index (units of f4) in the 2x2x2-tiled layout. Bijection on [0,NN).
__device__ __forceinline__ int rec_addr(int z, int y, int x) {
    return ((((z >> 1) * TT + (y >> 1)) * TT + (x >> 1)) << 3)
         + (((z & 1) << 2) | ((y & 1) << 1) | (x & 1));
}

// Modes: 0 = planar fp32 (stride NN/channel), 1 = tiled f4 (tiled thread
// order), 2 = F3 12B row-major (fallback, row-major thread order).
template <int SM, int DM>
__global__ __launch_bounds__(256) void diffeo_step(
    const void* __restrict__ srcv, void* __restrict__ dstv, float scale)
{
    int bid = blockIdx.x;
    int swz = (bid & (NXCD - 1)) * CHUNK + (bid >> 3);
    int gid = swz * 256 + threadIdx.x;

    int w, h, d;
    if constexpr (SM == 1 || DM == 1) {
        // gid is a record index in tiled space; decode voxel coords.
        int slot = gid & 7;
        int tile = gid >> 3;
        int tx = tile % TT;
        int t2 = tile / TT;
        int ty = t2 % TT;
        int tz = t2 / TT;
        w = (tx << 1) | (slot & 1);
        h = (ty << 1) | ((slot >> 1) & 1);
        d = (tz << 1) | (slot >> 2);
    } else {
        w = gid % WW;
        int t = gid / WW;
        h = t % HH;
        d = t / HH;
    }
    int idx = (d * HH + h) * WW + w;   // row-major voxel index (planar I/O)

    float f0, f1, f2;
    if constexpr (SM == 0) {
        const float* src = (const float*)srcv;
        f0 = src[idx] * scale;
        f1 = src[idx + NN] * scale;
        f2 = src[idx + 2 * NN] * scale;
    } else if constexpr (SM == 1) {
        const f4* s4 = (const f4*)srcv;
        f4 own = s4[gid];                        // coalesced: record idx == gid
        f0 = own.x * scale; f1 = own.y * scale; f2 = own.z * scale;
    } else {
        const F3* s3 = (const F3*)srcv;
        F3 own = s3[gid];
        f0 = own.x * scale; f1 = own.y * scale; f2 = own.z * scale;
    }

    float x = fminf(fmaxf((float)w + f2 * (0.5f * (WW - 1)), 0.0f), (float)(WW - 1));
    float y = fminf(fmaxf((float)h + f1 * (0.5f * (HH - 1)), 0.0f), (float)(HH - 1));
    float z = fminf(fmaxf((float)d + f0 * (0.5f * (DD - 1)), 0.0f), (float)(DD - 1));

    int x0 = (int)x;  float wx = x - (float)x0;
    int y0 = (int)y;  float wy = y - (float)y0;
    int z0 = (int)z;  float wz = z - (float)z0;
    int x1 = min(x0 + 1, WW - 1);
    int y1 = min(y0 + 1, HH - 1);
    int z1 = min(z0 + 1, DD - 1);

    float ox = 1.0f - wx, oy = 1.0f - wy, oz = 1.0f - wz;
    float w000 = ox * oy * oz, w001 = wx * oy * oz;
    float w010 = ox * wy * oz, w011 = wx * wy * oz;
    float w100 = ox * oy * wz, w101 = wx * oy * wz;
    float w110 = ox * wy * wz, w111 = wx * wy * wz;

    float v0, v1, v2;
    if constexpr (SM == 0) {
        const float* src = (const float*)srcv;
        int i000 = (z0 * HH + y0) * WW + x0, i001 = (z0 * HH + y0) * WW + x1;
        int i010 = (z0 * HH + y1) * WW + x0, i011 = (z0 * HH + y1) * WW + x1;
        int i100 = (z1 * HH + y0) * WW + x0, i101 = (z1 * HH + y0) * WW + x1;
        int i110 = (z1 * HH + y1) * WW + x0, i111 = (z1 * HH + y1) * WW + x1;
        float acc[3];
#pragma unroll
        for (int c = 0; c < 3; ++c) {
            const float* s = src + c * NN;
            acc[c] =
                w000 * s[i000] + w001 * s[i001] +
                w010 * s[i010] + w011 * s[i011] +
                w100 * s[i100] + w101 * s[i101] +
                w110 * s[i110] + w111 * s[i111];
        }
        v0 = acc[0]; v1 = acc[1]; v2 = acc[2];
    } else if constexpr (SM == 1) {
        const f4* s4 = (const f4*)srcv;
        int a000 = rec_addr(z0, y0, x0), a001 = rec_addr(z0, y0, x1);
        int a010 = rec_addr(z0, y1, x0), a011 = rec_addr(z0, y1, x1);
        int a100 = rec_addr(z1, y0, x0), a101 = rec_addr(z1, y0, x1);
        int a110 = rec_addr(z1, y1, x0), a111 = rec_addr(z1, y1, x1);
        f4 c000 = s4[a000];
        f4 c001 = s4[a001];
        f4 c010 = s4[a010];
        f4 c011 = s4[a011];
        f4 c100 = s4[a100];
        f4 c101 = s4[a101];
        f4 c110 = s4[a110];
        f4 c111 = s4[a111];
        // MLP fence: require all 8 loads resident before any FMA consumes one
        // -> the 8 global_load_dwordx4 issue back-to-back (max in-flight).
        asm volatile("" : "+v"(c000), "+v"(c001), "+v"(c010), "+v"(c011),
                          "+v"(c100), "+v"(c101), "+v"(c110), "+v"(c111));
        v0 = w000 * c000.x + w001 * c001.x + w010 * c010.x + w011 * c011.x
           + w100 * c100.x + w101 * c101.x + w110 * c110.x + w111 * c111.x;
        v1 = w000 * c000.y + w001 * c001.y + w010 * c010.y + w011 * c011.y
           + w100 * c100.y + w101 * c101.y + w110 * c110.y + w111 * c111.y;
        v2 = w000 * c000.z + w001 * c001.z + w010 * c010.z + w011 * c011.z
           + w100 * c100.z + w101 * c101.z + w110 * c110.z + w111 * c111.z;
    } else {
        const F3* s3 = (const F3*)srcv;
        int i000 = (z0 * HH + y0) * WW + x0, i001 = (z0 * HH + y0) * WW + x1;
        int i010 = (z0 * HH + y1) * WW + x0, i011 = (z0 * HH + y1) * WW + x1;
        int i100 = (z1 * HH + y0) * WW + x0, i101 = (z1 * HH + y0) * WW + x1;
        int i110 = (z1 * HH + y1) * WW + x0, i111 = (z1 * HH + y1) * WW + x1;
        F3 c000 = s3[i000], c001 = s3[i001], c010 = s3[i010], c011 = s3[i011];
        F3 c100 = s3[i100], c101 = s3[i101], c110 = s3[i110], c111 = s3[i111];
        v0 = w000 * c000.x + w001 * c001.x + w010 * c010.x + w011 * c011.x
           + w100 * c100.x + w101 * c101.x + w110 * c110.x + w111 * c111.x;
        v1 = w000 * c000.y + w001 * c001.y + w010 * c010.y + w011 * c011.y
           + w100 * c100.y + w101 * c101.y + w110 * c110.y + w111 * c111.y;
        v2 = w000 * c000.z + w001 * c001.z + w010 * c010.z + w011 * c011.z
           + w100 * c100.z + w101 * c101.z + w110 * c110.z + w111 * c111.z;
    }

    float o0 = f0 + scale * v0;
    float o1 = f1 + scale * v1;
    float o2 = f2 + scale * v2;
    if constexpr (DM == 0) {
        float* dst = (float*)dstv;
        dst[idx] = o0; dst[idx + NN] = o1; dst[idx + 2 * NN] = o2;
    } else if constexpr (DM == 1) {
        f4* d4 = (f4*)dstv;
        f4 o = { o0, o1, o2, 0.0f };
        d4[gid] = o;                               // coalesced full lines
    } else {
        F3* d3 = (F3*)dstv;
        F3 o = { o0, o1, o2 };
        d3[gid] = o;
    }
}

extern "C" void kernel_launch(void* const* d_in, const int* in_sizes, int n_in,
                              void* d_out, int out_size, void* d_ws, size_t ws_size,
                              hipStream_t stream) {
    const void* in = d_in[0];
    void* out = d_out;
    const float inv = 1.0f / 128.0f;  // 2^-TIME_STEP, TIME_STEP=7

    // Tiled path needs two f4*NN buffers (32B/voxel total) in ws.
    if (ws_size >= (size_t)NN * 32) {
        f4* qa = (f4*)d_ws;        // buffer A (113 MB)
        f4* qb = (f4*)d_ws + NN;   // buffer B (113 MB)
        diffeo_step<0, 1><<<NB, 256, 0, stream>>>(in, qa, inv);    // it1
        diffeo_step<1, 1><<<NB, 256, 0, stream>>>(qa, qb, 1.0f);   // it2
        diffeo_step<1, 1><<<NB, 256, 0, stream>>>(qb, qa, 1.0f);   // it3
        diffeo_step<1, 1><<<NB, 256, 0, stream>>>(qa, qb, 1.0f);   // it4
        diffeo_step<1, 1><<<NB, 256, 0, stream>>>(qb, qa, 1.0f);   // it5
        diffeo_step<1, 1><<<NB, 256, 0, stream>>>(qa, qb, 1.0f);   // it6
        diffeo_step<1, 0><<<NB, 256, 0, stream>>>(qb, out, 1.0f);  // it7
    } else {
        // Fallback: F3 12B interleaved ping-pong (R3/R4 proven path).
        void* ws = d_ws;
        diffeo_step<0, 2><<<NB, 256, 0, stream>>>(in,  out, inv);
        diffeo_step<2, 2><<<NB, 256, 0, stream>>>(out, ws,  1.0f);
        diffeo_step<2, 2><<<NB, 256, 0, stream>>>(ws,  out, 1.0f);
        diffeo_step<2, 2><<<NB, 256, 0, stream>>>(out, ws,  1.0f);
        diffeo_step<2, 2><<<NB, 256, 0, stream>>>(ws,  out, 1.0f);
        diffeo_step<2, 2><<<NB, 256, 0, stream>>>(out, ws,  1.0f);
        diffeo_step<2, 0><<<NB, 256, 0, stream>>>(ws,  out, 1.0f);
    }
}